// Round 1
// baseline (320.956 us; speedup 1.0000x reference)
//
#include <hip/hip_runtime.h>
#include <math.h>

#define NPTS 4096
#define NB 4
#define NPOINT 204
#define NGROUP (NB * NPOINT) /* 816 */
#define REPBLKS 256
#define REP_H 0.0005f

struct SmemFPS {
  float sx[NPTS], sy[NPTS], sz[NPTS];
  float rv[4];
  int ri[4];
  int cur;
};
struct SmemRep {
  float lists[4][64][5];
};
union SmemK1 {
  SmemFPS fps;
  SmemRep rep;
};

__device__ __forceinline__ void insert5(float (&s)[5], float v) {
  if (v < s[4]) {
    if (v < s[3]) {
      s[4] = s[3];
      if (v < s[2]) {
        s[3] = s[2];
        if (v < s[1]) {
          s[2] = s[1];
          if (v < s[0]) { s[1] = s[0]; s[0] = v; }
          else s[1] = v;
        } else s[2] = v;
      } else s[3] = v;
    } else s[4] = v;
  }
}

// merge two sorted-ascending 5-lists -> 5 smallest (sorted) into a
__device__ __forceinline__ void merge5(float (&a)[5], const float (&bin)[5]) {
  float A[6], Bv[6];
#pragma unroll
  for (int i = 0; i < 5; ++i) { A[i] = a[i]; Bv[i] = bin[i]; }
  A[5] = INFINITY; Bv[5] = INFINITY;
  float r[5];
#pragma unroll
  for (int k = 0; k < 5; ++k) {
    const bool ta = A[0] <= Bv[0];
    r[k] = ta ? A[0] : Bv[0];
#pragma unroll
    for (int i = 0; i < 5; ++i) {
      A[i]  = ta ? A[i + 1] : A[i];
      Bv[i] = ta ? Bv[i] : Bv[i + 1];
    }
  }
#pragma unroll
  for (int i = 0; i < 5; ++i) a[i] = r[i];
}

__device__ __forceinline__ float bcast_lane(float x, int k) {
  return __uint_as_float(__builtin_amdgcn_readlane(__float_as_uint(x), k));
}

// Blocks 0..3: FPS (one per batch). Blocks 4..259: repulsion (brute-force KNN top-5).
__global__ __launch_bounds__(256) void k1_fps_rep(const float* __restrict__ pcd,
                                                  float* __restrict__ centers,
                                                  float* __restrict__ repout) {
  __shared__ SmemK1 sm;
  const int t = threadIdx.x;
  if (blockIdx.x < NB) {
    // ------------------ FPS ------------------
    const int b = blockIdx.x;
    const float* __restrict__ P = pcd + (size_t)b * NPTS * 3;
    for (int i = t; i < NPTS; i += 256) {
      sm.fps.sx[i] = P[3 * i + 0];
      sm.fps.sy[i] = P[3 * i + 1];
      sm.fps.sz[i] = P[3 * i + 2];
    }
    __syncthreads();
    float px[16], py[16], pz[16], mind[16];
#pragma unroll
    for (int k = 0; k < 16; ++k) {
      const int i = t * 16 + k;  // contiguous chunk: in-thread ascending index
      px[k] = sm.fps.sx[i]; py[k] = sm.fps.sy[i]; pz[k] = sm.fps.sz[i];
      mind[k] = INFINITY;
    }
    int cur = 0;
    for (int s = 0; s < NPOINT; ++s) {
      const float cx = sm.fps.sx[cur], cy = sm.fps.sy[cur], cz = sm.fps.sz[cur];
      if (t == 0) {
        float* cp = centers + ((size_t)b * NPOINT + s) * 3;
        cp[0] = cx; cp[1] = cy; cp[2] = cz;
      }
      float bestv = -1.0f; int besti = 0;
#pragma unroll
      for (int k = 0; k < 16; ++k) {
        const float dx = px[k] - cx, dy = py[k] - cy, dz = pz[k] - cz;
        const float d = dx * dx + dy * dy + dz * dz;
        const float m = fminf(mind[k], d);
        mind[k] = m;
        if (m > bestv) { bestv = m; besti = t * 16 + k; }  // strict > => lowest idx on tie
      }
#pragma unroll
      for (int off = 32; off > 0; off >>= 1) {
        const float ov = __shfl_xor(bestv, off);
        const int oi = __shfl_xor(besti, off);
        if (ov > bestv || (ov == bestv && oi < besti)) { bestv = ov; besti = oi; }
      }
      if ((t & 63) == 0) { sm.fps.rv[t >> 6] = bestv; sm.fps.ri[t >> 6] = besti; }
      __syncthreads();
      if (t == 0) {
        float v = sm.fps.rv[0]; int bi = sm.fps.ri[0];
#pragma unroll
        for (int w = 1; w < 4; ++w) {
          const float vv = sm.fps.rv[w]; const int ii = sm.fps.ri[w];
          if (vv > v || (vv == v && ii < bi)) { v = vv; bi = ii; }
        }
        sm.fps.cur = bi;
      }
      __syncthreads();
      cur = sm.fps.cur;
    }
  } else {
    // ------------------ repulsion ------------------
    const int rblk = blockIdx.x - NB;       // 0..255
    const int b = rblk >> 6;                // batch
    const int qbase = (rblk & 63) * 64;     // 64 queries per block
    const float* __restrict__ P = pcd + (size_t)b * NPTS * 3;
    const int lane = t & 63;
    const int w = t >> 6;                   // wave = candidate subset (4 x 1024)
    const int q = qbase + lane;
    const float qx = P[3 * q + 0], qy = P[3 * q + 1], qz = P[3 * q + 2];
    float s5[5];
#pragma unroll
    for (int i = 0; i < 5; ++i) s5[i] = INFINITY;
    for (int c = 0; c < 16; ++c) {
      const int ci = (w << 10) + (c << 6) + lane;
      const float ox = P[3 * ci + 0], oy = P[3 * ci + 1], oz = P[3 * ci + 2];
#pragma unroll
      for (int k = 0; k < 64; ++k) {
        const float cxv = bcast_lane(ox, k);
        const float cyv = bcast_lane(oy, k);
        const float czv = bcast_lane(oz, k);
        const float dx = qx - cxv, dy = qy - cyv, dz = qz - czv;
        const float d2 = dx * dx + dy * dy + dz * dz;
        insert5(s5, d2);
      }
    }
#pragma unroll
    for (int i = 0; i < 5; ++i) sm.rep.lists[w][lane][i] = s5[i];
    __syncthreads();
    float tsum = 0.0f;
    if (w == 0) {
#pragma unroll
      for (int pw = 1; pw < 4; ++pw) {
        float bin[5];
#pragma unroll
        for (int i = 0; i < 5; ++i) bin[i] = sm.rep.lists[pw][lane][i];
        merge5(s5, bin);
      }
#pragma unroll
      for (int i = 1; i < 5; ++i) tsum += fmaxf(REP_H - s5[i] * s5[i], 0.0f);
    }
#pragma unroll
    for (int off = 32; off > 0; off >>= 1) tsum += __shfl_xor(tsum, off);
    if (t == 0) repout[rblk] = tsum;  // wave 0 holds the whole block's sum
  }
}

// One block per group (center); all 5 percentages handled in-block.
__global__ __launch_bounds__(256) void k2_uniform(const float* __restrict__ pcd,
                                                  const float* __restrict__ centers,
                                                  float* __restrict__ uloss) {
  __shared__ float selx[64], sely[64], selz[64];
  __shared__ float nnv[64];
  __shared__ int wsum[4];
  const int g = blockIdx.x;         // 0..815, g = b*NPOINT + c
  const int b = g / NPOINT;
  const int t = threadIdx.x;
  const float* __restrict__ P = pcd + (size_t)b * NPTS * 3;
  const float cxx = centers[(size_t)g * 3 + 0];
  const float cyy = centers[(size_t)g * 3 + 1];
  const float czz = centers[(size_t)g * 3 + 2];
  const float ca2 = cxx * cxx + cyy * cyy + czz * czz;
  const float4* __restrict__ P4 = (const float4*)P;
  float c[48];
#pragma unroll
  for (int m = 0; m < 12; ++m) {
    const float4 v = P4[t * 12 + m];
    c[4 * m + 0] = v.x; c[4 * m + 1] = v.y; c[4 * m + 2] = v.z; c[4 * m + 3] = v.w;
  }
  float d2r[16];
#pragma unroll
  for (int k = 0; k < 16; ++k) {
    const float x = c[3 * k], y = c[3 * k + 1], z = c[3 * k + 2];
    const float b2 = x * x + y * y + z * z;
    const float dt = cxx * x + cyy * y + czz * z;
    d2r[k] = fmaxf(ca2 + b2 - 2.0f * dt, 0.0f);  // same clamped formula as reference
  }
  const double pv[5] = {0.004, 0.006, 0.008, 0.01, 0.012};
  const int nsmp[5] = {16, 24, 32, 40, 49};
  const float EXPECT = (float)sqrt(M_PI / 4096.0);
  const int lane = t & 63, wv = t >> 6;
#pragma unroll 1
  for (int p = 0; p < 5; ++p) {
    const int K = nsmp[p];
    const double rd = sqrt(pv[p]);
    const float rr = (float)(rd * rd);
    unsigned mask = 0; int cnt = 0;
#pragma unroll
    for (int k = 0; k < 16; ++k) {
      if (d2r[k] < rr) { mask |= (1u << k); ++cnt; }
    }
    // inclusive scan of counts (first-K in ascending index order)
    int incl = cnt;
#pragma unroll
    for (int off = 1; off < 64; off <<= 1) {
      const int nv = __shfl_up(incl, off);
      if (lane >= off) incl += nv;
    }
    if (lane == 63) wsum[wv] = incl;
    __syncthreads();
    int base = incl - cnt;
    for (int ww = 0; ww < wv; ++ww) base += wsum[ww];
    const int total = wsum[0] + wsum[1] + wsum[2] + wsum[3];
    int pos = base;
#pragma unroll
    for (int k = 0; k < 16; ++k) {
      if (mask & (1u << k)) {
        if (pos < K) { selx[pos] = c[3 * k]; sely[pos] = c[3 * k + 1]; selz[pos] = c[3 * k + 2]; }
        ++pos;
      }
    }
    const int realc = total < K ? total : K;
    for (int j = realc + t; j < K; j += 256) { selx[j] = 0.0f; sely[j] = 0.0f; selz[j] = 0.0f; }
    __syncthreads();
    if (t < K) {
      const float xi = selx[t], yi = sely[t], zi = selz[t];
      const float ai = xi * xi + yi * yi + zi * zi;
      float m = INFINITY;
      for (int j = 0; j < K; ++j) {
        if (j == t) continue;
        const float xj = selx[j], yj = sely[j], zj = selz[j];
        const float aj = xj * xj + yj * yj + zj * zj;
        float d = ai + aj - 2.0f * (xi * xj + yi * yj + zi * zj);
        d = fmaxf(d, 0.0f);
        m = fminf(m, d);
      }
      nnv[t] = m + 1e-8f;
    }
    __syncthreads();
    if (t == 0) {
      double ssum = 0.0;
      for (int j = 0; j < K; ++j) ssum += (double)nnv[j];
      const float u = (float)(ssum / (double)K);
      const float df = u - EXPECT;
      uloss[p * NGROUP + g] = df * df / (EXPECT + 1e-8f);
    }
    __syncthreads();
  }
}

__global__ __launch_bounds__(256) void k3_reduce(const float* __restrict__ uloss,
                                                 const float* __restrict__ repout,
                                                 float* __restrict__ out) {
  __shared__ double sd[256];
  const int t = threadIdx.x;
  const double wl[5] = {0.16, 0.36, 0.64, 1.0, 1.44};  // (p*100)^2
  double acc = 0.0;
#pragma unroll
  for (int p = 0; p < 5; ++p) {
    double a2 = 0.0;
    for (int i = t; i < NGROUP; i += 256) a2 += (double)uloss[p * NGROUP + i];
    acc += wl[p] * a2;
  }
  acc *= (1.0 / ((double)NGROUP * 5.0));
  acc += (double)repout[t] * (1.0 / 65536.0);  // mean over (B,N,4) = 4*4096*4
  sd[t] = acc;
  __syncthreads();
  for (int s = 128; s > 0; s >>= 1) {
    if (t < s) sd[t] += sd[t + s];
    __syncthreads();
  }
  if (t == 0) out[0] = (float)sd[0];
}

extern "C" void kernel_launch(void* const* d_in, const int* in_sizes, int n_in,
                              void* d_out, int out_size, void* d_ws, size_t ws_size,
                              hipStream_t stream) {
  const float* pcd = (const float*)d_in[0];
  float* out = (float*)d_out;
  float* centers = (float*)d_ws;              // 4*204*3 = 2448 floats
  float* uloss = centers + NB * NPOINT * 3;   // 5*816 = 4080 floats
  float* repout = uloss + 5 * NGROUP;         // 256 floats
  k1_fps_rep<<<NB + REPBLKS, 256, 0, stream>>>(pcd, centers, repout);
  k2_uniform<<<NGROUP, 256, 0, stream>>>(pcd, centers, uloss);
  k3_reduce<<<1, 256, 0, stream>>>(uloss, repout, out);
}

// Round 2
// 225.792 us; speedup vs baseline: 1.4215x; 1.4215x over previous
//
#include <hip/hip_runtime.h>
#include <math.h>

#define NPTS 4096
#define NB 4
#define NPOINT 204
#define NGROUP (NB * NPOINT) /* 816 */
#define REPBLKS 256
#define REP_H 0.0005f

struct SmemFPS {
  float sx[NPTS], sy[NPTS], sz[NPTS];
  unsigned wv[2][4];   // per-wave winner value (float bits), double-buffered by iter parity
  unsigned wix[2][4];  // per-wave winner global index
};
struct SmemRep {
  float lists[4][64][5];
};
union SmemK1 {
  SmemFPS fps;
  SmemRep rep;
};

__device__ __forceinline__ void insert5(float (&s)[5], float v) {
  if (v < s[4]) {
    if (v < s[3]) {
      s[4] = s[3];
      if (v < s[2]) {
        s[3] = s[2];
        if (v < s[1]) {
          s[2] = s[1];
          if (v < s[0]) { s[1] = s[0]; s[0] = v; }
          else s[1] = v;
        } else s[2] = v;
      } else s[3] = v;
    } else s[4] = v;
  }
}

// merge two sorted-ascending 5-lists -> 5 smallest (sorted) into a
__device__ __forceinline__ void merge5(float (&a)[5], const float (&bin)[5]) {
  float A[6], Bv[6];
#pragma unroll
  for (int i = 0; i < 5; ++i) { A[i] = a[i]; Bv[i] = bin[i]; }
  A[5] = INFINITY; Bv[5] = INFINITY;
  float r[5];
#pragma unroll
  for (int k = 0; k < 5; ++k) {
    const bool ta = A[0] <= Bv[0];
    r[k] = ta ? A[0] : Bv[0];
#pragma unroll
    for (int i = 0; i < 5; ++i) {
      A[i]  = ta ? A[i + 1] : A[i];
      Bv[i] = ta ? Bv[i] : Bv[i + 1];
    }
  }
#pragma unroll
  for (int i = 0; i < 5; ++i) a[i] = r[i];
}

__device__ __forceinline__ float bcast_lane(float x, int k) {
  return __uint_as_float(__builtin_amdgcn_readlane(__float_as_uint(x), k));
}

// Wave64 max-reduce of a nonnegative-float's bits via DPP; result broadcast
// (uniform) from lane 63. Dependent-chain ~6 VALU-latency ops instead of 6
// ds_bpermute round-trips.
__device__ __forceinline__ unsigned wave_max_bits(unsigned x) {
  int v = (int)x;
  v = max((unsigned)v, (unsigned)__builtin_amdgcn_update_dpp(0, v, 0x111, 0xF, 0xF, false)); // row_shr:1
  v = max((unsigned)v, (unsigned)__builtin_amdgcn_update_dpp(0, v, 0x112, 0xF, 0xF, false)); // row_shr:2
  v = max((unsigned)v, (unsigned)__builtin_amdgcn_update_dpp(0, v, 0x114, 0xF, 0xF, false)); // row_shr:4
  v = max((unsigned)v, (unsigned)__builtin_amdgcn_update_dpp(0, v, 0x118, 0xF, 0xF, false)); // row_shr:8
  v = max((unsigned)v, (unsigned)__builtin_amdgcn_update_dpp(0, v, 0x142, 0xF, 0xF, false)); // row_bcast:15
  v = max((unsigned)v, (unsigned)__builtin_amdgcn_update_dpp(0, v, 0x143, 0xF, 0xF, false)); // row_bcast:31
  return (unsigned)__builtin_amdgcn_readlane(v, 63);
}

// Blocks 0..3: FPS (one per batch). Blocks 4..259: repulsion (brute-force KNN top-5).
__global__ __launch_bounds__(256) void k1_fps_rep(const float* __restrict__ pcd,
                                                  float* __restrict__ centers,
                                                  float* __restrict__ repout) {
  __shared__ SmemK1 sm;
  const int t = threadIdx.x;
  if (blockIdx.x < NB) {
    // ------------------ FPS ------------------
    const int b = blockIdx.x;
    const float* __restrict__ P = pcd + (size_t)b * NPTS * 3;
    const float4* __restrict__ P4 = (const float4*)P;
    float c[48];
#pragma unroll
    for (int m = 0; m < 12; ++m) {
      const float4 v = P4[t * 12 + m];
      c[4 * m + 0] = v.x; c[4 * m + 1] = v.y; c[4 * m + 2] = v.z; c[4 * m + 3] = v.w;
    }
    float px[16], py[16], pz[16], mind[16];
#pragma unroll
    for (int k = 0; k < 16; ++k) {
      px[k] = c[3 * k]; py[k] = c[3 * k + 1]; pz[k] = c[3 * k + 2];
      mind[k] = INFINITY;
      const int i = t * 16 + k;
      sm.fps.sx[i] = px[k]; sm.fps.sy[i] = py[k]; sm.fps.sz[i] = pz[k];
    }
    __syncthreads();
    const int lane = t & 63, w = t >> 6;
    int cur = 0;
    for (int s = 0; s < NPOINT; ++s) {
      const float cx = sm.fps.sx[cur], cy = sm.fps.sy[cur], cz = sm.fps.sz[cur];
      if (t == 0) {
        float* cp = centers + ((size_t)b * NPOINT + s) * 3;
        cp[0] = cx; cp[1] = cy; cp[2] = cz;
      }
      unsigned bmax = 0u;
#pragma unroll
      for (int k = 0; k < 16; ++k) {
        const float dx = px[k] - cx, dy = py[k] - cy, dz = pz[k] - cz;
        const float d = dx * dx + dy * dy + dz * dz;
        const float m = fminf(mind[k], d);
        mind[k] = m;
        bmax = max(bmax, __float_as_uint(m));  // d>=0: uint order == float order
      }
      const unsigned wm = wave_max_bits(bmax);  // wave-uniform max
      // lowest local k achieving the wave max (descending scan keeps lowest)
      int li = 16;
#pragma unroll
      for (int k = 15; k >= 0; --k)
        if (__float_as_uint(mind[k]) == wm) li = k;
      const unsigned long long mk = __ballot(li < 16);
      const int L = (int)__builtin_ctzll(mk);             // lowest lane with the max
      const int lk = __builtin_amdgcn_readlane(li, L);    // its local index
      const unsigned widx = (unsigned)(((w * 64 + L) << 4) + lk);
      const int par = s & 1;
      if (lane == 0) { sm.fps.wv[par][w] = wm; sm.fps.wix[par][w] = widx; }
      __syncthreads();
      // every thread redundantly picks the global winner (tie -> lowest wave)
      unsigned bv = sm.fps.wv[par][0];
      unsigned bi = sm.fps.wix[par][0];
#pragma unroll
      for (int ww = 1; ww < 4; ++ww) {
        const unsigned vv = sm.fps.wv[par][ww];
        const unsigned ii = sm.fps.wix[par][ww];
        if (vv > bv) { bv = vv; bi = ii; }
      }
      cur = (int)bi;
    }
  } else {
    // ------------------ repulsion ------------------
    const int rblk = blockIdx.x - NB;       // 0..255
    const int b = rblk >> 6;                // batch
    const int qbase = (rblk & 63) * 64;     // 64 queries per block
    const float* __restrict__ P = pcd + (size_t)b * NPTS * 3;
    const int lane = t & 63;
    const int w = t >> 6;                   // wave = candidate subset (4 x 1024)
    const int q = qbase + lane;
    const float qx = P[3 * q + 0], qy = P[3 * q + 1], qz = P[3 * q + 2];
    float s5[5];
#pragma unroll
    for (int i = 0; i < 5; ++i) s5[i] = INFINITY;
    for (int c = 0; c < 16; ++c) {
      const int ci = (w << 10) + (c << 6) + lane;
      const float ox = P[3 * ci + 0], oy = P[3 * ci + 1], oz = P[3 * ci + 2];
#pragma unroll
      for (int k = 0; k < 64; ++k) {
        const float cxv = bcast_lane(ox, k);
        const float cyv = bcast_lane(oy, k);
        const float czv = bcast_lane(oz, k);
        const float dx = qx - cxv, dy = qy - cyv, dz = qz - czv;
        const float d2 = dx * dx + dy * dy + dz * dz;
        insert5(s5, d2);
      }
    }
#pragma unroll
    for (int i = 0; i < 5; ++i) sm.rep.lists[w][lane][i] = s5[i];
    __syncthreads();
    float tsum = 0.0f;
    if (w == 0) {
#pragma unroll
      for (int pw = 1; pw < 4; ++pw) {
        float bin[5];
#pragma unroll
        for (int i = 0; i < 5; ++i) bin[i] = sm.rep.lists[pw][lane][i];
        merge5(s5, bin);
      }
#pragma unroll
      for (int i = 1; i < 5; ++i) tsum += fmaxf(REP_H - s5[i] * s5[i], 0.0f);
    }
#pragma unroll
    for (int off = 32; off > 0; off >>= 1) tsum += __shfl_xor(tsum, off);
    if (t == 0) repout[rblk] = tsum;  // wave 0 holds the whole block's sum
  }
}

// One block per group (center); all 5 percentages handled in-block.
__global__ __launch_bounds__(256) void k2_uniform(const float* __restrict__ pcd,
                                                  const float* __restrict__ centers,
                                                  float* __restrict__ uloss) {
  __shared__ float selx[64], sely[64], selz[64];
  __shared__ float nnv[64];
  __shared__ int wsum[4];
  const int g = blockIdx.x;         // 0..815, g = b*NPOINT + c
  const int b = g / NPOINT;
  const int t = threadIdx.x;
  const float* __restrict__ P = pcd + (size_t)b * NPTS * 3;
  const float cxx = centers[(size_t)g * 3 + 0];
  const float cyy = centers[(size_t)g * 3 + 1];
  const float czz = centers[(size_t)g * 3 + 2];
  const float ca2 = cxx * cxx + cyy * cyy + czz * czz;
  const float4* __restrict__ P4 = (const float4*)P;
  float c[48];
#pragma unroll
  for (int m = 0; m < 12; ++m) {
    const float4 v = P4[t * 12 + m];
    c[4 * m + 0] = v.x; c[4 * m + 1] = v.y; c[4 * m + 2] = v.z; c[4 * m + 3] = v.w;
  }
  float d2r[16];
#pragma unroll
  for (int k = 0; k < 16; ++k) {
    const float x = c[3 * k], y = c[3 * k + 1], z = c[3 * k + 2];
    const float b2 = x * x + y * y + z * z;
    const float dt = cxx * x + cyy * y + czz * z;
    d2r[k] = fmaxf(ca2 + b2 - 2.0f * dt, 0.0f);  // same clamped formula as reference
  }
  const double pv[5] = {0.004, 0.006, 0.008, 0.01, 0.012};
  const int nsmp[5] = {16, 24, 32, 40, 49};
  const float EXPECT = (float)sqrt(M_PI / 4096.0);
  const int lane = t & 63, wv = t >> 6;
#pragma unroll 1
  for (int p = 0; p < 5; ++p) {
    const int K = nsmp[p];
    const double rd = sqrt(pv[p]);
    const float rr = (float)(rd * rd);
    unsigned mask = 0; int cnt = 0;
#pragma unroll
    for (int k = 0; k < 16; ++k) {
      if (d2r[k] < rr) { mask |= (1u << k); ++cnt; }
    }
    // inclusive scan of counts (first-K in ascending index order)
    int incl = cnt;
#pragma unroll
    for (int off = 1; off < 64; off <<= 1) {
      const int nv = __shfl_up(incl, off);
      if (lane >= off) incl += nv;
    }
    if (lane == 63) wsum[wv] = incl;
    __syncthreads();
    int base = incl - cnt;
    for (int ww = 0; ww < wv; ++ww) base += wsum[ww];
    const int total = wsum[0] + wsum[1] + wsum[2] + wsum[3];
    int pos = base;
#pragma unroll
    for (int k = 0; k < 16; ++k) {
      if (mask & (1u << k)) {
        if (pos < K) { selx[pos] = c[3 * k]; sely[pos] = c[3 * k + 1]; selz[pos] = c[3 * k + 2]; }
        ++pos;
      }
    }
    const int realc = total < K ? total : K;
    for (int j = realc + t; j < K; j += 256) { selx[j] = 0.0f; sely[j] = 0.0f; selz[j] = 0.0f; }
    __syncthreads();
    if (t < K) {
      const float xi = selx[t], yi = sely[t], zi = selz[t];
      const float ai = xi * xi + yi * yi + zi * zi;
      float m = INFINITY;
      for (int j = 0; j < K; ++j) {
        if (j == t) continue;
        const float xj = selx[j], yj = sely[j], zj = selz[j];
        const float aj = xj * xj + yj * yj + zj * zj;
        float d = ai + aj - 2.0f * (xi * xj + yi * yj + zi * zj);
        d = fmaxf(d, 0.0f);
        m = fminf(m, d);
      }
      nnv[t] = m + 1e-8f;
    }
    __syncthreads();
    if (t == 0) {
      double ssum = 0.0;
      for (int j = 0; j < K; ++j) ssum += (double)nnv[j];
      const float u = (float)(ssum / (double)K);
      const float df = u - EXPECT;
      uloss[p * NGROUP + g] = df * df / (EXPECT + 1e-8f);
    }
    __syncthreads();
  }
}

__global__ __launch_bounds__(256) void k3_reduce(const float* __restrict__ uloss,
                                                 const float* __restrict__ repout,
                                                 float* __restrict__ out) {
  __shared__ double sd[256];
  const int t = threadIdx.x;
  const double wl[5] = {0.16, 0.36, 0.64, 1.0, 1.44};  // (p*100)^2
  double acc = 0.0;
#pragma unroll
  for (int p = 0; p < 5; ++p) {
    double a2 = 0.0;
    for (int i = t; i < NGROUP; i += 256) a2 += (double)uloss[p * NGROUP + i];
    acc += wl[p] * a2;
  }
  acc *= (1.0 / ((double)NGROUP * 5.0));
  acc += (double)repout[t] * (1.0 / 65536.0);  // mean over (B,N,4) = 4*4096*4
  sd[t] = acc;
  __syncthreads();
  for (int s = 128; s > 0; s >>= 1) {
    if (t < s) sd[t] += sd[t + s];
    __syncthreads();
  }
  if (t == 0) out[0] = (float)sd[0];
}

extern "C" void kernel_launch(void* const* d_in, const int* in_sizes, int n_in,
                              void* d_out, int out_size, void* d_ws, size_t ws_size,
                              hipStream_t stream) {
  const float* pcd = (const float*)d_in[0];
  float* out = (float*)d_out;
  float* centers = (float*)d_ws;              // 4*204*3 = 2448 floats
  float* uloss = centers + NB * NPOINT * 3;   // 5*816 = 4080 floats
  float* repout = uloss + 5 * NGROUP;         // 256 floats
  k1_fps_rep<<<NB + REPBLKS, 256, 0, stream>>>(pcd, centers, repout);
  k2_uniform<<<NGROUP, 256, 0, stream>>>(pcd, centers, uloss);
  k3_reduce<<<1, 256, 0, stream>>>(uloss, repout, out);
}